// Round 1
// baseline (259.603 us; speedup 1.0000x reference)
//
#include <hip/hip_runtime.h>
#include <math.h>

#define NCELLS 1024
#define INDIM 256
#define HID 512
#define ODIM 256
#define INNER 128
#define NPAIRS 512

__device__ inline float sigm(float x){ return 1.0f/(1.0f + expf(-x)); }
__device__ inline float tanh3(float x){ return x*fmaf(x*x, -0.33333334f, 1.0f); }

// ---- K0: combined = [x | hiddens]  (1024 x 768)
__global__ void k_combined(const float* __restrict__ x, const float* __restrict__ hiddens,
                           float* __restrict__ comb){
    int r = blockIdx.y;
    int k = blockIdx.x*256 + threadIdx.x;
    float v = (k < INDIM) ? x[k] : hiddens[(size_t)r*HID + (k - INDIM)];
    comb[(size_t)r*(INDIM+HID) + k] = v;
}

// ---- generic f32 GEMM: C = A[:, acoff:acoff+K] @ W^T + bias, optional relu.
// blockIdx.z selects parameter set (for fused a/g launches).
#define BM 64
#define BN 64
#define BK 32
__global__ __launch_bounds__(256) void k_gemm(
    const float* __restrict__ A, int lda,
    const float* __restrict__ W0, const float* __restrict__ b0, float* __restrict__ C0, int acoff0,
    const float* __restrict__ W1, const float* __restrict__ b1, float* __restrict__ C1, int acoff1,
    int ldw, int ldc, int K, int relu)
{
    const float* W = W0; const float* bias = b0; float* C = C0; int acoff = acoff0;
    if (blockIdx.z == 1){ W = W1; bias = b1; C = C1; acoff = acoff1; }
    const int m0 = blockIdx.y * BM;
    const int n0 = blockIdx.x * BN;
    __shared__ __align__(16) float At[BK][BM+4];
    __shared__ __align__(16) float Wt[BK][BN+4];
    const int tid  = threadIdx.x;
    const int lrow = tid & 63;     // 0..63
    const int seg  = tid >> 6;     // 0..3  (8 k-elements each)
    const int tx   = tid & 15, ty = tid >> 4;
    const bool w4  = ((ldw & 3) == 0);
    float acc[4][4] = {};
    for (int k0 = 0; k0 < K; k0 += BK) {
        const float* ap = A + (size_t)(m0+lrow)*lda + acoff + k0 + seg*8;
        float4 a0 = *(const float4*)ap;
        float4 a1 = *(const float4*)(ap+4);
        const float* wp = W + (size_t)(n0+lrow)*ldw + k0 + seg*8;
        float wl[8];
        if (w4){
            float4 w0v = *(const float4*)wp;
            float4 w1v = *(const float4*)(wp+4);
            wl[0]=w0v.x; wl[1]=w0v.y; wl[2]=w0v.z; wl[3]=w0v.w;
            wl[4]=w1v.x; wl[5]=w1v.y; wl[6]=w1v.z; wl[7]=w1v.w;
        } else {
            #pragma unroll
            for (int i=0;i<8;++i) wl[i] = wp[i];
        }
        const int kb = seg*8;
        At[kb+0][lrow]=a0.x; At[kb+1][lrow]=a0.y; At[kb+2][lrow]=a0.z; At[kb+3][lrow]=a0.w;
        At[kb+4][lrow]=a1.x; At[kb+5][lrow]=a1.y; At[kb+6][lrow]=a1.z; At[kb+7][lrow]=a1.w;
        #pragma unroll
        for (int i=0;i<8;++i) Wt[kb+i][lrow]=wl[i];
        __syncthreads();
        #pragma unroll
        for (int kk=0;kk<BK;++kk){
            float4 av = *(const float4*)&At[kk][ty*4];
            float4 wv = *(const float4*)&Wt[kk][tx*4];
            float a_[4]={av.x,av.y,av.z,av.w};
            float w_[4]={wv.x,wv.y,wv.z,wv.w};
            #pragma unroll
            for (int i=0;i<4;++i)
                #pragma unroll
                for (int j=0;j<4;++j)
                    acc[i][j] = fmaf(a_[i], w_[j], acc[i][j]);
        }
        __syncthreads();
    }
    #pragma unroll
    for (int i=0;i<4;++i){
        const int r = m0 + ty*4 + i;
        float4 ov;
        float* o = (float*)&ov;
        #pragma unroll
        for (int j=0;j<4;++j){
            float v = acc[i][j] + bias[n0 + tx*4 + j];
            if (relu) v = fmaxf(v, 0.0f);
            o[j] = v;
        }
        *(float4*)&C[(size_t)r*ldc + n0 + tx*4] = ov;
    }
}

// ---- K3: OUT = OUTa - OUTg ; tension[r] = mean(OUT[r]^2)
__global__ __launch_bounds__(256) void k_subtension(const float* __restrict__ Ca,
        const float* __restrict__ Cg, float* __restrict__ OUT, float* __restrict__ tension){
    int r = blockIdx.x, c = threadIdx.x;
    float v = Ca[(size_t)r*ODIM+c] - Cg[(size_t)r*ODIM+c];
    OUT[(size_t)r*ODIM+c] = v;
    float s = v*v;
    #pragma unroll
    for (int m=1;m<64;m<<=1) s += __shfl_xor(s, m);
    __shared__ float red[4];
    int lane = c & 63, wv = c >> 6;
    if (lane==0) red[wv]=s;
    __syncthreads();
    if (c==0) tension[r] = (red[0]+red[1]+red[2]+red[3]) * (1.0f/ODIM);
}

// ---- K6: GRU elementwise (adds the tension*w_ih[:,256] column on the fly)
__global__ __launch_bounds__(512) void k_gru(const float* __restrict__ GI, const float* __restrict__ GH,
    const float* __restrict__ tension, const float* __restrict__ w_ih,
    const float* __restrict__ hiddens, float* __restrict__ newh)
{
    int r = blockIdx.x, j = threadIdx.x;
    float tv = tension[r];
    const float* gi = GI + (size_t)r*1536;
    const float* gh = GH + (size_t)r*1536;
    float ir  = gi[j]       + tv * w_ih[(size_t)j*257 + 256];
    float iz  = gi[512+j]   + tv * w_ih[(size_t)(512+j)*257 + 256];
    float inn = gi[1024+j]  + tv * w_ih[(size_t)(1024+j)*257 + 256];
    float hr = gh[j], hz = gh[512+j], hn = gh[1024+j];
    float rg = sigm(ir + hr);
    float zg = sigm(iz + hz);
    float n  = tanhf(inn + rg*hn);
    newh[(size_t)r*HID + j] = (1.0f - zg)*n + zg*hiddens[(size_t)r*HID + j];
}

// ---- K7: pair entanglement mixing (the 512 MiB streaming kernel)
__global__ __launch_bounds__(512) void k_mix(const float* __restrict__ newh,
        const float* __restrict__ bell, const float* __restrict__ ent,
        float* __restrict__ hmix)
{
    const int p = blockIdx.x;
    const int tid = threadIdx.x;
    const int lane = tid & 63;
    const int wv = tid >> 6;                 // 8 waves
    __shared__ __align__(16) float hi[HID], hj[HID];
    __shared__ __align__(16) float colacc[8][HID];
    const float* __restrict__ rot = bell + (size_t)p * HID * HID;
    hi[tid] = newh[(size_t)(2*p)*HID + tid];
    hj[tid] = newh[(size_t)(2*p+1)*HID + tid];
    __syncthreads();
    const float e = 1.0f/(1.0f + expf(-ent[p]));
    const float one_e = 1.0f - e;
    const int c0 = lane<<2, c1 = 256 + (lane<<2);
    float hjr[8];
    #pragma unroll
    for (int k=0;k<4;++k){ hjr[k]=hj[c0+k]; hjr[4+k]=hj[c1+k]; }
    float aj[8] = {};
    #pragma unroll 2
    for (int r = wv; r < HID; r += 8) {
        float4 v0 = *(const float4*)(rot + (size_t)r*HID + c0);
        float4 v1 = *(const float4*)(rot + (size_t)r*HID + c1);
        float t[8];
        t[0]=tanh3(v0.x); t[1]=tanh3(v0.y); t[2]=tanh3(v0.z); t[3]=tanh3(v0.w);
        t[4]=tanh3(v1.x); t[5]=tanh3(v1.y); t[6]=tanh3(v1.z); t[7]=tanh3(v1.w);
        float hir = hi[r];
        float rp = 0.0f;
        #pragma unroll
        for (int k=0;k<8;++k){ rp = fmaf(t[k], hjr[k], rp); aj[k] = fmaf(t[k], hir, aj[k]); }
        #pragma unroll
        for (int m=1;m<64;m<<=1) rp += __shfl_xor(rp, m);
        if (lane == 0) hmix[(size_t)(2*p)*HID + r] = one_e*hir + e*rp;
    }
    *(float4*)&colacc[wv][c0] = make_float4(aj[0],aj[1],aj[2],aj[3]);
    *(float4*)&colacc[wv][c1] = make_float4(aj[4],aj[5],aj[6],aj[7]);
    __syncthreads();
    float s = 0.0f;
    #pragma unroll
    for (int w=0;w<8;++w) s += colacc[w][tid];
    hmix[(size_t)(2*p+1)*HID + tid] = -(one_e*hj[tid] + e*s);
}

// ---- K8: per-faction mean (post-mix mean == post-sync mean)
__global__ __launch_bounds__(512) void k_fmean(const float* __restrict__ hmix, float* __restrict__ fmean){
    int f = blockIdx.x, d = threadIdx.x;
    float s = 0.0f;
    for (int c=0;c<128;++c) s += hmix[(size_t)((f<<7)+c)*HID + d];
    fmean[f*HID + d] = s*(1.0f/128.0f);
}

// ---- K9: faction sync + debate, writes final h
__global__ __launch_bounds__(512) void k_final_h(const float* __restrict__ hmix,
        const float* __restrict__ fmean, const int* __restrict__ stepp, float* __restrict__ hout){
    int cell = blockIdx.x, d = threadIdx.x;
    int f = cell >> 7;
    float v = 0.85f*hmix[(size_t)cell*HID + d] + 0.15f*fmean[f*HID + d];
    if (*stepp > 5 && (cell & 127) < 32){
        float g = 0.0f;
        #pragma unroll
        for (int q=0;q<8;++q) g += fmean[q*HID + d];
        g *= 0.125f;
        v = 0.85f*v + 0.15f*g;
    }
    hout[(size_t)cell*HID + d] = v;
}

// ---- K10a: softmax(tension) -> weights ; avg_tension -> d_out[256]
__global__ __launch_bounds__(1024) void k_softmax(const float* __restrict__ tension,
        float* __restrict__ weights, float* __restrict__ avg_out){
    int t = threadIdx.x;
    int lane = t & 63, wv = t >> 6;
    float tv = tension[t];
    __shared__ float red[16], redb[16], SS[2];
    float m = tv;
    #pragma unroll
    for (int s=1;s<64;s<<=1) m = fmaxf(m, __shfl_xor(m, s));
    if (lane==0) red[wv] = m;
    __syncthreads();
    if (t==0){ float mm=red[0]; for(int i=1;i<16;++i) mm=fmaxf(mm,red[i]); SS[1]=mm; }
    __syncthreads();
    float M = SS[1];
    float ex = expf(tv - M);
    float s2 = ex, s3 = tv;
    #pragma unroll
    for (int s=1;s<64;s<<=1){ s2 += __shfl_xor(s2,s); s3 += __shfl_xor(s3,s); }
    if (lane==0){ red[wv]=s2; redb[wv]=s3; }
    __syncthreads();
    if (t==0){
        float a=0,b=0;
        for(int i=0;i<16;++i){ a+=red[i]; b+=redb[i]; }
        SS[0]=a;
        avg_out[0] = b*(1.0f/1024.0f);
    }
    __syncthreads();
    weights[t] = ex / SS[0];
}

// ---- K10b: partial weighted sums of OUT rows
__global__ __launch_bounds__(256) void k_copart(const float* __restrict__ OUT,
        const float* __restrict__ weights, float* __restrict__ copart){
    int b = blockIdx.x, c = threadIdx.x;
    float s = 0.0f;
    for (int r = b*32; r < b*32+32; ++r) s = fmaf(weights[r], OUT[(size_t)r*ODIM + c], s);
    copart[b*ODIM + c] = s;
}

// ---- K10c: finish combined_out, apply head
__global__ __launch_bounds__(256) void k_pred(const float* __restrict__ copart,
        const float* __restrict__ head_w, const float* __restrict__ head_b, float* __restrict__ pred){
    int o = threadIdx.x;
    __shared__ float co[ODIM];
    float s = 0.0f;
    for (int b=0;b<32;++b) s += copart[b*ODIM + o];
    co[o] = s;
    __syncthreads();
    float acc = head_b[o];
    for (int c=0;c<ODIM;++c) acc = fmaf(head_w[(size_t)o*ODIM + c], co[c], acc);
    pred[o] = acc;
}

extern "C" void kernel_launch(void* const* d_in, const int* in_sizes, int n_in,
                              void* d_out, int out_size, void* d_ws, size_t ws_size,
                              hipStream_t stream)
{
    const float* x      = (const float*)d_in[0];
    const float* hiddens= (const float*)d_in[1];
    const float* W1a=(const float*)d_in[2];  const float* b1a=(const float*)d_in[3];
    const float* W2a=(const float*)d_in[4];  const float* b2a=(const float*)d_in[5];
    const float* W1g=(const float*)d_in[6];  const float* b1g=(const float*)d_in[7];
    const float* W2g=(const float*)d_in[8];  const float* b2g=(const float*)d_in[9];
    const float* w_ih=(const float*)d_in[10]; const float* w_hh=(const float*)d_in[11];
    const float* b_ih=(const float*)d_in[12]; const float* b_hh=(const float*)d_in[13];
    const float* head_w=(const float*)d_in[14]; const float* head_b=(const float*)d_in[15];
    const float* ent=(const float*)d_in[16]; const float* bell=(const float*)d_in[17];
    const int*   stepp=(const int*)d_in[18];
    float* out = (float*)d_out;

    float* ws = (float*)d_ws;
    size_t off = 0;
    float* comb    = ws + off; off += (size_t)1024*768;
    float* H1      = ws + off; off += (size_t)1024*256;
    float* OUTa    = ws + off; off += (size_t)1024*256;
    float* OUTg    = ws + off; off += (size_t)1024*256;
    float* OUT     = ws + off; off += (size_t)1024*256;
    float* tension = ws + off; off += 1024;
    float* GI      = ws + off; off += (size_t)1024*1536;
    float* GH      = ws + off; off += (size_t)1024*1536;
    float* newh    = ws + off; off += (size_t)1024*512;
    float* hmix    = ws + off; off += (size_t)1024*512;
    float* fmean   = ws + off; off += 8*512;
    float* weights = ws + off; off += 1024;
    float* copart  = ws + off; off += 32*256;

    k_combined<<<dim3(3,1024), 256, 0, stream>>>(x, hiddens, comb);
    // layer1: H1[:, :128]=relu(comb@W1a^T+b1a), H1[:,128:]=relu(comb@W1g^T+b1g)
    k_gemm<<<dim3(2,16,2),256,0,stream>>>(comb, 768,
        W1a, b1a, H1, 0,
        W1g, b1g, H1+128, 0,
        768, 256, 768, 1);
    // layer2: OUTa = H1a@W2a^T+b2a ; OUTg = H1g@W2g^T+b2g
    k_gemm<<<dim3(4,16,2),256,0,stream>>>(H1, 256,
        W2a, b2a, OUTa, 0,
        W2g, b2g, OUTg, 128,
        128, 256, 128, 0);
    k_subtension<<<1024,256,0,stream>>>(OUTa, OUTg, OUT, tension);
    // GRU input-side: GI = OUT@w_ih[:, :256]^T + b_ih  (tension column folded into k_gru)
    k_gemm<<<dim3(24,16,1),256,0,stream>>>(OUT, 256,
        w_ih, b_ih, GI, 0,
        w_ih, b_ih, GI, 0,
        257, 1536, 256, 0);
    // GRU hidden-side: GH = hiddens@w_hh^T + b_hh
    k_gemm<<<dim3(24,16,1),256,0,stream>>>(hiddens, 512,
        w_hh, b_hh, GH, 0,
        w_hh, b_hh, GH, 0,
        512, 1536, 512, 0);
    k_gru<<<1024,512,0,stream>>>(GI, GH, tension, w_ih, hiddens, newh);
    k_mix<<<512,512,0,stream>>>(newh, bell, ent, hmix);
    k_fmean<<<8,512,0,stream>>>(hmix, fmean);
    k_final_h<<<1024,512,0,stream>>>(hmix, fmean, stepp, out + 257);
    k_softmax<<<1,1024,0,stream>>>(tension, weights, out + 256);
    k_copart<<<32,256,0,stream>>>(OUT, weights, copart);
    k_pred<<<1,256,0,stream>>>(copart, head_w, head_b, out);
}

// Round 3
// 164.126 us; speedup vs baseline: 1.5817x; 1.5817x over previous
//
#include <hip/hip_runtime.h>
#include <math.h>

#define NCELLS 1024
#define INDIM 256
#define HID 512
#define ODIM 256
#define NPAIRS 512

typedef __attribute__((ext_vector_type(4))) float f32x4;
typedef __attribute__((ext_vector_type(8))) short short8;
typedef unsigned short ushort_t;

__device__ inline float sigm(float x){ return 1.0f/(1.0f + expf(-x)); }
__device__ inline float tanh3(float x){ return x*fmaf(x*x, -0.33333334f, 1.0f); }
__device__ inline ushort_t f2bf(float f){
    unsigned u = __float_as_uint(f);
    return (ushort_t)((u + 0x7FFFu + ((u>>16)&1u)) >> 16);
}

// ============ K_CVT: build bf16 fragment-order operands ============
// frag layout: elem [rtile][ktile][lane][j] = src[rtile*16+(lane&15)][ktile*32+(lane>>4)*8+j]
// jobs (tiles): Wc1(16x24=384) Wc2(16x8=128) wih(96x8=768) whh(96x16=1536)
//              comb(64x24=1536) hidd(64x16=1024)  + 32 tail blocks (biases, wcol)
__global__ __launch_bounds__(64) void k_cvt(
    const float* __restrict__ x, const float* __restrict__ hiddens,
    const float* __restrict__ W1a, const float* __restrict__ W1g,
    const float* __restrict__ W2a, const float* __restrict__ W2g,
    const float* __restrict__ w_ih, const float* __restrict__ w_hh,
    const float* __restrict__ b1a, const float* __restrict__ b1g,
    const float* __restrict__ b2a, const float* __restrict__ b2g,
    ushort_t* __restrict__ Wc1f, ushort_t* __restrict__ Wc2f,
    ushort_t* __restrict__ wihf, ushort_t* __restrict__ whhf,
    ushort_t* __restrict__ combf, ushort_t* __restrict__ hiddf,
    float* __restrict__ bc1, float* __restrict__ bc2, float* __restrict__ wcol)
{
    const int b = blockIdx.x;
    const int lane = threadIdx.x;
    if (b >= 5376){ // tail: scalar jobs
        int t = (b - 5376)*64 + lane;
        if (t < 256)       bc1[t] = (t<128) ? b1a[t] : b1g[t-128];
        else if (t < 512)  { int i=t-256; bc2[i] = b2a[i] - b2g[i]; }
        else               { int i=t-512; wcol[i] = w_ih[(size_t)i*257 + 256]; }
        return;
    }
    int job, idx, KT; ushort_t* dst;
    if      (b < 384){  job=0; idx=b;      KT=24; dst=Wc1f; }
    else if (b < 512){  job=1; idx=b-384;  KT=8;  dst=Wc2f; }
    else if (b < 1280){ job=2; idx=b-512;  KT=8;  dst=wihf; }
    else if (b < 2816){ job=3; idx=b-1280; KT=16; dst=whhf; }
    else if (b < 4352){ job=4; idx=b-2816; KT=24; dst=combf;}
    else             {  job=5; idx=b-4352; KT=16; dst=hiddf;}
    const int rt = idx / KT, kt = idx % KT;
    const int r  = rt*16 + (lane & 15);
    const int kb = kt*32 + (lane >> 4)*8;
    float v[8];
    if (job == 0){
        const float* s = (r < 128) ? (W1a + (size_t)r*768) : (W1g + (size_t)(r-128)*768);
        #pragma unroll
        for (int j=0;j<8;++j) v[j] = s[kb+j];
    } else if (job == 1){
        if (kb < 128){ const float* s = W2a + (size_t)r*128 + kb;
            #pragma unroll
            for (int j=0;j<8;++j) v[j] = s[j];
        } else { const float* s = W2g + (size_t)r*128 + (kb-128);
            #pragma unroll
            for (int j=0;j<8;++j) v[j] = -s[j];
        }
    } else if (job == 2){
        const float* s = w_ih + (size_t)r*257 + kb;
        #pragma unroll
        for (int j=0;j<8;++j) v[j] = s[j];
    } else if (job == 3){
        const float* s = w_hh + (size_t)r*512 + kb;
        #pragma unroll
        for (int j=0;j<8;++j) v[j] = s[j];
    } else if (job == 4){
        if (kb < 256){
            #pragma unroll
            for (int j=0;j<8;++j) v[j] = x[kb+j];
        } else { const float* s = hiddens + (size_t)r*512 + (kb-256);
            #pragma unroll
            for (int j=0;j<8;++j) v[j] = s[j];
        }
    } else {
        const float* s = hiddens + (size_t)r*512 + kb;
        #pragma unroll
        for (int j=0;j<8;++j) v[j] = s[j];
    }
    short8 o;
    #pragma unroll
    for (int j=0;j<8;++j) o[j] = (short)f2bf(v[j]);
    ((short8*)dst)[(size_t)idx*64 + lane] = o;
}

// ============ MFMA GEMM: C[M x N] = A @ W^T + bias ============
// A,B prearranged in fragment order. Block=256thr (4 waves stacked on M),
// wave computes 16 x 32 output (2 n-tiles). grid = (N/32, M/64).
// EPI 0: f32 row-major store.  EPI 1: relu + bf16 A-frag store to Cf.
template<int KT, int EPI>
__global__ __launch_bounds__(256) void k_mm(
    const ushort_t* __restrict__ Af, const ushort_t* __restrict__ Bf,
    const float* __restrict__ bias, float* __restrict__ C,
    ushort_t* __restrict__ Cf, int N)
{
    const int lane = threadIdx.x & 63;
    const int w    = threadIdx.x >> 6;
    const int mtile = blockIdx.y*4 + w;
    const int nt0   = blockIdx.x*2;
    const short8* A8 = (const short8*)Af;
    const short8* B8 = (const short8*)Bf;
    f32x4 acc0 = {0.f,0.f,0.f,0.f}, acc1 = {0.f,0.f,0.f,0.f};
    #pragma unroll 4
    for (int kt=0; kt<KT; ++kt){
        short8 a  = A8[((size_t)mtile*KT + kt)*64 + lane];
        short8 b0 = B8[((size_t)nt0*KT + kt)*64 + lane];
        short8 b1 = B8[((size_t)(nt0+1)*KT + kt)*64 + lane];
        acc0 = __builtin_amdgcn_mfma_f32_16x16x32_bf16(a, b0, acc0, 0,0,0);
        acc1 = __builtin_amdgcn_mfma_f32_16x16x32_bf16(a, b1, acc1, 0,0,0);
    }
    if (EPI == 0){
        const int r0 = mtile*16 + (lane>>4)*4;
        const int c0 = nt0*16 + (lane&15);
        const float bb0 = bias[c0], bb1 = bias[c0+16];
        #pragma unroll
        for (int i=0;i<4;++i){
            C[(size_t)(r0+i)*N + c0]    = acc0[i] + bb0;
            C[(size_t)(r0+i)*N + c0+16] = acc1[i] + bb1;
        }
    } else {
        __shared__ float lt[4][16][33];
        const int rr = (lane>>4)*4, cc = lane&15;
        const float bb0 = bias[nt0*16 + cc], bb1 = bias[nt0*16 + 16 + cc];
        #pragma unroll
        for (int i=0;i<4;++i){
            lt[w][rr+i][cc]    = fmaxf(acc0[i] + bb0, 0.f);
            lt[w][rr+i][16+cc] = fmaxf(acc1[i] + bb1, 0.f);
        }
        __syncthreads();
        const int m = lane & 15, kb = (lane>>4)*8;
        short8 o;
        #pragma unroll
        for (int j=0;j<8;++j) o[j] = (short)f2bf(lt[w][m][kb+j]);
        ((short8*)Cf)[((size_t)mtile*gridDim.x + blockIdx.x)*64 + lane] = o;
    }
}

// ============ tension + OUT -> bf16 A-frag ============
__global__ __launch_bounds__(512) void k_tension_cvt(const float* __restrict__ OUT,
        float* __restrict__ tension, ushort_t* __restrict__ Of)
{
    const int mt = blockIdx.x;
    const int lane = threadIdx.x & 63, wv = threadIdx.x >> 6; // wv = ktile (8)
    const int m = mt*16 + (lane&15);
    const int k = wv*32 + (lane>>4)*8;
    const float* p = OUT + (size_t)m*ODIM + k;
    float4 v0 = *(const float4*)p;
    float4 v1 = *(const float4*)(p+4);
    float s = v0.x*v0.x + v0.y*v0.y + v0.z*v0.z + v0.w*v0.w
            + v1.x*v1.x + v1.y*v1.y + v1.z*v1.z + v1.w*v1.w;
    short8 o;
    o[0]=(short)f2bf(v0.x); o[1]=(short)f2bf(v0.y); o[2]=(short)f2bf(v0.z); o[3]=(short)f2bf(v0.w);
    o[4]=(short)f2bf(v1.x); o[5]=(short)f2bf(v1.y); o[6]=(short)f2bf(v1.z); o[7]=(short)f2bf(v1.w);
    ((short8*)Of)[((size_t)mt*8 + wv)*64 + lane] = o;
    s += __shfl_xor(s, 16); s += __shfl_xor(s, 32);
    __shared__ float red[8][16];
    if (lane < 16) red[wv][lane] = s;
    __syncthreads();
    if (threadIdx.x < 16){
        float t = 0.f;
        #pragma unroll
        for (int q=0;q<8;++q) t += red[q][threadIdx.x];
        tension[mt*16 + threadIdx.x] = t * (1.0f/ODIM);
    }
}

// ============ fused GRU + pair entanglement mixing ============
__global__ __launch_bounds__(512) void k_mix(const float* __restrict__ GI,
        const float* __restrict__ GH, const float* __restrict__ tension,
        const float* __restrict__ wcol, const float* __restrict__ hiddens,
        const float* __restrict__ bell, const float* __restrict__ ent,
        float* __restrict__ hmix)
{
    const int p = blockIdx.x;
    const int tid = threadIdx.x;
    const int lane = tid & 63;
    const int wv = tid >> 6;
    __shared__ __align__(16) float hi[HID], hj[HID];
    __shared__ __align__(16) float colacc[8][HID];
    // GRU prologue: newh for cells 2p -> hi, 2p+1 -> hj
    {
        const int j = tid;
        const float wj0 = wcol[j], wj1 = wcol[512+j], wj2 = wcol[1024+j];
        #pragma unroll
        for (int c01=0; c01<2; ++c01){
            const int cell = 2*p + c01;
            const float tv = tension[cell];
            const float* gi = GI + (size_t)cell*1536;
            const float* gh = GH + (size_t)cell*1536;
            float rg = sigm(gi[j]      + tv*wj0 + gh[j]);
            float zg = sigm(gi[512+j]  + tv*wj1 + gh[512+j]);
            float nn = tanhf(gi[1024+j]+ tv*wj2 + rg*gh[1024+j]);
            float h  = (1.f - zg)*nn + zg*hiddens[(size_t)cell*HID + j];
            (c01 ? hj : hi)[j] = h;
        }
    }
    __syncthreads();
    const float* __restrict__ rot = bell + (size_t)p * HID * HID;
    const float e = 1.0f/(1.0f + expf(-ent[p]));
    const float one_e = 1.0f - e;
    const int c0 = lane<<2, c1 = 256 + (lane<<2);
    float hjr[8];
    #pragma unroll
    for (int k=0;k<4;++k){ hjr[k]=hj[c0+k]; hjr[4+k]=hj[c1+k]; }
    float aj[8] = {};
    #pragma unroll 2
    for (int r = wv; r < HID; r += 8) {
        float4 v0 = *(const float4*)(rot + (size_t)r*HID + c0);
        float4 v1 = *(const float4*)(rot + (size_t)r*HID + c1);
        float t[8];
        t[0]=tanh3(v0.x); t[1]=tanh3(v0.y); t[2]=tanh3(v0.z); t[3]=tanh3(v0.w);
        t[4]=tanh3(v1.x); t[5]=tanh3(v1.y); t[6]=tanh3(v1.z); t[7]=tanh3(v1.w);
        const float hir = hi[r];
        float rp = 0.0f;
        #pragma unroll
        for (int k=0;k<8;++k){ rp = fmaf(t[k], hjr[k], rp); aj[k] = fmaf(t[k], hir, aj[k]); }
        #pragma unroll
        for (int m=1;m<64;m<<=1) rp += __shfl_xor(rp, m);
        if (lane == 0) hmix[(size_t)(2*p)*HID + r] = one_e*hir + e*rp;
    }
    *(float4*)&colacc[wv][c0] = make_float4(aj[0],aj[1],aj[2],aj[3]);
    *(float4*)&colacc[wv][c1] = make_float4(aj[4],aj[5],aj[6],aj[7]);
    __syncthreads();
    float s = 0.0f;
    #pragma unroll
    for (int w=0;w<8;++w) s += colacc[w][tid];
    hmix[(size_t)(2*p+1)*HID + tid] = -(one_e*hj[tid] + e*s);
}

// ============ faction mean ============
__global__ __launch_bounds__(512) void k_fmean(const float* __restrict__ hmix, float* __restrict__ fmean){
    int f = blockIdx.x, d = threadIdx.x;
    float s = 0.0f;
    for (int c=0;c<128;++c) s += hmix[(size_t)((f<<7)+c)*HID + d];
    fmean[f*HID + d] = s*(1.0f/128.0f);
}

// ============ faction sync + debate ============
__global__ __launch_bounds__(512) void k_final_h(const float* __restrict__ hmix,
        const float* __restrict__ fmean, const int* __restrict__ stepp, float* __restrict__ hout){
    int cell = blockIdx.x, d = threadIdx.x;
    int f = cell >> 7;
    float v = 0.85f*hmix[(size_t)cell*HID + d] + 0.15f*fmean[f*HID + d];
    if (*stepp > 5 && (cell & 127) < 32){
        float g = 0.0f;
        #pragma unroll
        for (int q=0;q<8;++q) g += fmean[q*HID + d];
        g *= 0.125f;
        v = 0.85f*v + 0.15f*g;
    }
    hout[(size_t)cell*HID + d] = v;
}

// ============ softmax(tension) + avg ============
__global__ __launch_bounds__(1024) void k_softmax(const float* __restrict__ tension,
        float* __restrict__ weights, float* __restrict__ avg_out){
    int t = threadIdx.x;
    int lane = t & 63, wv = t >> 6;
    float tv = tension[t];
    __shared__ float red[16], redb[16], SS[2];
    float m = tv;
    #pragma unroll
    for (int s=1;s<64;s<<=1) m = fmaxf(m, __shfl_xor(m, s));
    if (lane==0) red[wv] = m;
    __syncthreads();
    if (t==0){ float mm=red[0]; for(int i=1;i<16;++i) mm=fmaxf(mm,red[i]); SS[1]=mm; }
    __syncthreads();
    float M = SS[1];
    float ex = expf(tv - M);
    float s2 = ex, s3 = tv;
    #pragma unroll
    for (int s=1;s<64;s<<=1){ s2 += __shfl_xor(s2,s); s3 += __shfl_xor(s3,s); }
    if (lane==0){ red[wv]=s2; redb[wv]=s3; }
    __syncthreads();
    if (t==0){
        float a=0,b=0;
        for(int i=0;i<16;++i){ a+=red[i]; b+=redb[i]; }
        SS[0]=a;
        avg_out[0] = b*(1.0f/1024.0f);
    }
    __syncthreads();
    weights[t] = ex / SS[0];
}

// ============ weighted row-sum partials ============
__global__ __launch_bounds__(256) void k_copart(const float* __restrict__ OUT,
        const float* __restrict__ weights, float* __restrict__ copart){
    int b = blockIdx.x, c = threadIdx.x;
    float s = 0.0f;
    for (int r = b*32; r < b*32+32; ++r) s = fmaf(weights[r], OUT[(size_t)r*ODIM + c], s);
    copart[b*ODIM + c] = s;
}

// ============ head ============
__global__ __launch_bounds__(256) void k_pred(const float* __restrict__ copart,
        const float* __restrict__ head_w, const float* __restrict__ head_b, float* __restrict__ pred){
    int o = threadIdx.x;
    __shared__ float co[ODIM];
    float s = 0.0f;
    for (int b=0;b<32;++b) s += copart[b*ODIM + o];
    co[o] = s;
    __syncthreads();
    float acc = head_b[o];
    for (int c=0;c<ODIM;++c) acc = fmaf(head_w[(size_t)o*ODIM + c], co[c], acc);
    pred[o] = acc;
}

extern "C" void kernel_launch(void* const* d_in, const int* in_sizes, int n_in,
                              void* d_out, int out_size, void* d_ws, size_t ws_size,
                              hipStream_t stream)
{
    const float* x      = (const float*)d_in[0];
    const float* hiddens= (const float*)d_in[1];
    const float* W1a=(const float*)d_in[2];  const float* b1a=(const float*)d_in[3];
    const float* W2a=(const float*)d_in[4];  const float* b2a=(const float*)d_in[5];
    const float* W1g=(const float*)d_in[6];  const float* b1g=(const float*)d_in[7];
    const float* W2g=(const float*)d_in[8];  const float* b2g=(const float*)d_in[9];
    const float* w_ih=(const float*)d_in[10]; const float* w_hh=(const float*)d_in[11];
    const float* b_ih=(const float*)d_in[12]; const float* b_hh=(const float*)d_in[13];
    const float* head_w=(const float*)d_in[14]; const float* head_b=(const float*)d_in[15];
    const float* ent=(const float*)d_in[16]; const float* bell=(const float*)d_in[17];
    const int*   stepp=(const int*)d_in[18];
    float* out = (float*)d_out;

    char* wsb = (char*)d_ws;
    size_t off = 0;
    auto carve = [&](size_t bytes)->char*{ char* p = wsb + off; off += (bytes + 63) & ~(size_t)63; return p; };
    ushort_t* combf = (ushort_t*)carve((size_t)1024*768*2);
    ushort_t* hiddf = (ushort_t*)carve((size_t)1024*512*2);
    ushort_t* Wc1f  = (ushort_t*)carve((size_t)256*768*2);
    ushort_t* Wc2f  = (ushort_t*)carve((size_t)256*256*2);
    ushort_t* wihf  = (ushort_t*)carve((size_t)1536*256*2);
    ushort_t* whhf  = (ushort_t*)carve((size_t)1536*512*2);
    ushort_t* H1f   = (ushort_t*)carve((size_t)1024*256*2);
    ushort_t* Of    = (ushort_t*)carve((size_t)1024*256*2);
    float* bc1   = (float*)carve(256*4);
    float* bc2   = (float*)carve(256*4);
    float* wcol  = (float*)carve(1536*4);
    float* OUT   = (float*)carve((size_t)1024*256*4);
    float* tension=(float*)carve(1024*4);
    float* GI    = (float*)carve((size_t)1024*1536*4);
    float* GH    = (float*)carve((size_t)1024*1536*4);
    float* hmix  = (float*)carve((size_t)1024*512*4);
    float* fmean = (float*)carve(8*512*4);
    float* weights=(float*)carve(1024*4);
    float* copart =(float*)carve(32*256*4);

    k_cvt<<<5408, 64, 0, stream>>>(x, hiddens, W1a, W1g, W2a, W2g, w_ih, w_hh,
                                   b1a, b1g, b2a, b2g,
                                   Wc1f, Wc2f, wihf, whhf, combf, hiddf, bc1, bc2, wcol);
    // L1: H1 = relu([x|hiddens] @ [W1a;W1g]^T + bc1), bf16 A-frag out
    k_mm<24,1><<<dim3(8,16), 256, 0, stream>>>(combf, Wc1f, bc1, nullptr, H1f, 256);
    // L2: OUT = H1 @ [W2a|-W2g]^T + (b2a-b2g), f32 out
    k_mm<8,0><<<dim3(8,16), 256, 0, stream>>>(H1f, Wc2f, bc2, OUT, nullptr, 256);
    k_tension_cvt<<<64, 512, 0, stream>>>(OUT, tension, Of);
    // GH: hiddens @ w_hh^T + b_hh
    k_mm<16,0><<<dim3(48,16), 256, 0, stream>>>(hiddf, whhf, b_hh, GH, nullptr, 1536);
    // GI: OUT @ w_ih[:,:256]^T + b_ih  (tension column folded into k_mix via wcol)
    k_mm<8,0><<<dim3(48,16), 256, 0, stream>>>(Of, wihf, b_ih, GI, nullptr, 1536);
    k_mix<<<512, 512, 0, stream>>>(GI, GH, tension, wcol, hiddens, bell, ent, hmix);
    k_fmean<<<8, 512, 0, stream>>>(hmix, fmean);
    k_final_h<<<1024, 512, 0, stream>>>(hmix, fmean, stepp, out + 257);
    k_softmax<<<1, 1024, 0, stream>>>(tension, weights, out + 256);
    k_copart<<<32, 256, 0, stream>>>(OUT, weights, copart);
    k_pred<<<1, 256, 0, stream>>>(copart, head_w, head_b, out);
}